// Round 1
// 224.334 us; speedup vs baseline: 1.0043x; 1.0043x over previous
//
#include <hip/hip_runtime.h>

#define DEVINL __device__ __forceinline__

DEVINL float fmax4(float4 v) { return fmaxf(fmaxf(v.x, v.y), fmaxf(v.z, v.w)); }
DEVINL float4 max44(float4 a, float4 b) {
    float4 r; r.x = fmaxf(a.x, b.x); r.y = fmaxf(a.y, b.y);
    r.z = fmaxf(a.z, b.z); r.w = fmaxf(a.w, b.w); return r;
}

// Compile-time memory barrier: pins issue order; loads above cannot sink.
#define MEMBAR() asm volatile("" ::: "memory")

// ---------------- R6: uniform-unit pipelined phase 1 ----------------
// Every tensor decomposes into contiguous 1792-float "units" (7 float4/lane):
//   t4 (8,16,448,448): task (cb,ph) band = 16x448 = 4 units (4 rows x 448 each)
//   t3 (8,32,224,224): task band 8x224   = 1 unit;  7168 units, linear
//   t2 (8,64,112,112): task band 16x112  = 1 unit;  3584 units, linear
//   t1 (8,128,56,56):  4 merged bands 32x56 = 1 unit; 1792 units, linear
// One wave = 4 units = 28 KB, software-pipelined depth 2 (A/B reg buffers):
// >=7 float4 loads stay in flight across each unit's reduce/LDS/gather tail.
//
// ws float offsets: p1[8][128][28][28] @0, p2[8][64][28][28] @802816,
//                   p3[8][32][28][28] @1204224, p4[8][16][28][28] @1404928
#define O1 0
#define O2 802816
#define O3 1204224
#define O4 1404928
#define WS_FLOATS 1505280

// wave-class boundaries (wave id w)
#define WE4 3584    // t4: 3584 waves, 1 task (4 chunks) each
#define WE3 5376    // t3: 1792 waves x 4 tasks
#define WE2 6272    // t2:  896 waves x 4 tasks
#define WE1 6720    // t1m: 448 waves x 4 merged-tasks
// grid = 6720/4 = 1680 blocks

#define LD7(DST, PTR)                                                     \
    { _Pragma("unroll") for (int k = 0; k < 7; ++k)                        \
          DST[k] = *(const float4*)((PTR) + k * 256); }

__global__ __launch_bounds__(256, 4) void pool_all(
    const float* __restrict__ t1, const float* __restrict__ t2,
    const float* __restrict__ t3, const float* __restrict__ t4,
    float* __restrict__ ws)
{
    __shared__ __align__(16) float scratch[4 * 896];
    const int tid  = threadIdx.x;
    const int lane = tid & 63;
    const int w    = blockIdx.x * 4 + (tid >> 6);
    float* sm = &scratch[(tid >> 6) * 896];

    if (w < WE4) {
        // -------- t4 k=16: one task = 4 chunks (4 rows x 448 each) --------
        // chunk pos p=k*64+lane: r=p/112 (row-in-chunk), col4=p%112.
        // acc[k] = max over chunks => max over rows {r,4+r,8+r,12+r} at col4.
        const float* base = t4 + (size_t)w * 7168 + 4 * lane;
        float4 A[7], B[7], acc[7];
        LD7(A, base);                 // chunk 0   (7 in flight)
        LD7(B, base + 1792);          // chunk 1   (14 in flight)
        MEMBAR();
        #pragma unroll
        for (int k = 0; k < 7; ++k) acc[k] = A[k];          // wait -> vmcnt(7)
        LD7(A, base + 3584);          // chunk 2   (14 in flight)
        MEMBAR();
        #pragma unroll
        for (int k = 0; k < 7; ++k) acc[k] = max44(acc[k], B[k]);  // vmcnt(7)
        LD7(B, base + 5376);          // chunk 3   (14 in flight)
        MEMBAR();
        #pragma unroll
        for (int k = 0; k < 7; ++k) acc[k] = max44(acc[k], A[k]);  // vmcnt(7)
        #pragma unroll
        for (int k = 0; k < 7; ++k) acc[k] = max44(acc[k], B[k]);  // vmcnt(0)
        // identity LDS write (coalesced): sm[p] = col4-max over 16 rows/4
        #pragma unroll
        for (int k = 0; k < 7; ++k) sm[k * 64 + lane] = fmax4(acc[k]);
        MEMBAR();
        // out col j <- col4 4j..4j+3, row classes 0..3
        if (lane < 28) {
            float4 a = *(const float4*)&sm[0 * 112 + 4 * lane];
            float4 b = *(const float4*)&sm[1 * 112 + 4 * lane];
            float4 c = *(const float4*)&sm[2 * 112 + 4 * lane];
            float4 d = *(const float4*)&sm[3 * 112 + 4 * lane];
            ws[O4 + w * 28 + lane] = fmax4(max44(max44(a, b), max44(c, d)));
        }
    } else if (w < WE3) {
        // -------- t3 k=8: 4 independent tasks (8 rows x 224 each) --------
        // p=k*64+lane: row=p/56, col4=p%56. out col j <- col4 {2j,2j+1}.
        const int t0 = (w - WE4) * 4;
        const float* base = t3 + (size_t)t0 * 1792 + 4 * lane;
        float4 A[7], B[7];
        LD7(A, base);
        LD7(B, base + 1792);
        MEMBAR();
        #define T3_UNIT(VV, i)                                                 \
        {                                                                      \
            float* smh = sm + ((i) & 1) * 448;                                 \
            _Pragma("unroll") for (int k = 0; k < 7; ++k)                      \
                smh[k * 64 + lane] = fmax4(VV[k]);       /* vmcnt wait VV */   \
            if ((i) + 2 < 4) LD7(VV, base + ((i) + 2) * 1792);                 \
            MEMBAR();                                                          \
            if (lane < 28) {                                                   \
                float m = fmaxf(smh[2 * lane], smh[2 * lane + 1]);             \
                _Pragma("unroll") for (int r = 1; r < 8; ++r)                  \
                    m = fmaxf(m, fmaxf(smh[r * 56 + 2 * lane],                 \
                                       smh[r * 56 + 2 * lane + 1]));           \
                ws[O3 + (t0 + (i)) * 28 + lane] = m;                           \
            }                                                                  \
        }
        T3_UNIT(A, 0)
        T3_UNIT(B, 1)
        T3_UNIT(A, 2)
        T3_UNIT(B, 3)
    } else if (w < WE2) {
        // -------- t2 k=4: 4 independent tasks (16 rows x 112 each) --------
        // p=k*64+lane: row=p/28, pc=p%28 (one float4 = one 4-col window).
        const int t0 = (w - WE3) * 4;
        const float* base = t2 + (size_t)t0 * 1792 + 4 * lane;
        float4 A[7], B[7];
        LD7(A, base);
        LD7(B, base + 1792);
        MEMBAR();
        #define T2_UNIT(VV, i)                                                 \
        {                                                                      \
            float* smh = sm + ((i) & 1) * 448;                                 \
            _Pragma("unroll") for (int k = 0; k < 7; ++k)                      \
                smh[k * 64 + lane] = fmax4(VV[k]);                             \
            if ((i) + 2 < 4) LD7(VV, base + ((i) + 2) * 1792);                 \
            MEMBAR();                                                          \
            if (lane < 56) {                                                   \
                const int pr0 = lane / 28, pc = lane % 28;                     \
                _Pragma("unroll") for (int h = 0; h < 2; ++h) {                \
                    const int pr = pr0 + 2 * h;                                \
                    float m = fmaxf(fmaxf(smh[(4 * pr + 0) * 28 + pc],         \
                                          smh[(4 * pr + 1) * 28 + pc]),        \
                                    fmaxf(smh[(4 * pr + 2) * 28 + pc],         \
                                          smh[(4 * pr + 3) * 28 + pc]));       \
                    ws[O2 + (t0 + (i)) * 112 + pr * 28 + pc] = m;              \
                }                                                              \
            }                                                                  \
        }
        T2_UNIT(A, 0)
        T2_UNIT(B, 1)
        T2_UNIT(A, 2)
        T2_UNIT(B, 3)
    } else {
        // -------- t1 k=2: 4 merged-tasks, each = 32 rows x 56 cols --------
        // float4 idx p=k*64+lane (0..447): r=p/14, c=p%14 -> half-max pairs
        // sm[r*28+2c]=max(x,y), +1=max(z,w). Gather: out idx (pr*28+j):
        // max(sm[2pr*28+j], sm[(2pr+1)*28+j]); 448 outputs, 7/lane (all 64).
        const int t0 = (w - WE2) * 4;
        const float* base = t1 + (size_t)t0 * 1792 + 4 * lane;
        float4 A[7], B[7];
        LD7(A, base);
        LD7(B, base + 1792);
        MEMBAR();
        #define T1_UNIT(VV, i)                                                 \
        {                                                                      \
            _Pragma("unroll") for (int k = 0; k < 7; ++k) {                    \
                const int p = k * 64 + lane;                                   \
                const int r = p / 14, c = p % 14;                              \
                float2 h;                                                      \
                h.x = fmaxf(VV[k].x, VV[k].y);                                 \
                h.y = fmaxf(VV[k].z, VV[k].w);                                 \
                *(float2*)&sm[r * 28 + 2 * c] = h;                             \
            }                                                                  \
            if ((i) + 2 < 4) LD7(VV, base + ((i) + 2) * 1792);                 \
            MEMBAR();                                                          \
            _Pragma("unroll") for (int h = 0; h < 7; ++h) {                    \
                const int idx = h * 64 + lane;                                 \
                const int q = idx / 28, j = idx % 28;                          \
                ws[O1 + (t0 + (i)) * 448 + idx] =                              \
                    fmaxf(sm[q * 56 + j], sm[q * 56 + j + 28]);                \
            }                                                                  \
        }
        T1_UNIT(A, 0)
        T1_UNIT(B, 1)
        T1_UNIT(A, 2)
        T1_UNIT(B, 3)
    }
}

__global__ __launch_bounds__(256) void combine(
    const float* __restrict__ ws, const float* __restrict__ ff,
    float* __restrict__ out)
{
    const int i4 = blockIdx.x * 256 + threadIdx.x;   // out float4 index
    const int pw4 = i4 % 7;
    const int ph  = (i4 / 7) % 28;
    const int c   = (i4 / 196) % 256;
    const int b   = i4 / 50176;
    const int ppw = ph * 7 + pw4;
    const float4* W = (const float4*)ws;
    float4 a1 = W[O1 / 4 + (b * 128 + (c & 127)) * 196 + ppw];
    float4 a2 = W[O2 / 4 + (b * 64  + (c & 63))  * 196 + ppw];
    float4 a3 = W[O3 / 4 + (b * 32  + (c & 31))  * 196 + ppw];
    float4 a4 = W[O4 / 4 + (b * 16  + (c & 15))  * 196 + ppw];
    float4 f  = ((const float4*)ff)[i4];
    float4 o;
    o.x = fmaxf(a1.x + a2.x + a3.x + a4.x + f.x, 0.0f);
    o.y = fmaxf(a1.y + a2.y + a3.y + a4.y + f.y, 0.0f);
    o.z = fmaxf(a1.z + a2.z + a3.z + a4.z + f.z, 0.0f);
    o.w = fmaxf(a1.w + a2.w + a3.w + a4.w + f.w, 0.0f);
    ((float4*)out)[i4] = o;
}

// ---------------- fallback (R3 single-kernel) if ws too small ----------------
__global__ __launch_bounds__(256) void fused_pool_relu(
    const float* __restrict__ t1, const float* __restrict__ t2,
    const float* __restrict__ t3, const float* __restrict__ t4,
    const float* __restrict__ ff, float* __restrict__ out)
{
    const int pwq = blockIdx.x, ph = blockIdx.y, b = blockIdx.z;
    const int tid = threadIdx.x;
    const int pw0 = pwq * 4;
    __shared__ __align__(16) float p1[128 * 4];
    __shared__ __align__(16) float p2[64 * 4];
    __shared__ __align__(16) float p3[32 * 4];
    __shared__ __align__(16) float p4[16 * 4];
    {
        const int g = tid >> 4, l = tid & 15;
        const float* base = t4 + ((size_t)(b * 16 + g) * 448 + ph * 16) * 448
                          + pw0 * 16 + l * 4;
        float4 v[8];
        #pragma unroll
        for (int r = 0; r < 8; ++r) v[r] = *(const float4*)(base + r * 448);
        float4 acc = v[0];
        #pragma unroll
        for (int r = 1; r < 8; ++r) acc = max44(acc, v[r]);
        #pragma unroll
        for (int r = 8; r < 16; ++r) v[r - 8] = *(const float4*)(base + r * 448);
        #pragma unroll
        for (int r = 0; r < 8; ++r) acc = max44(acc, v[r]);
        float m = fmax4(acc);
        m = fmaxf(m, __shfl_xor(m, 1));
        m = fmaxf(m, __shfl_xor(m, 2));
        if ((l & 3) == 0) p4[g * 4 + (l >> 2)] = m;
    }
    {
        const int g = tid >> 3, l = tid & 7;
        const float* base = t3 + ((size_t)(b * 32 + g) * 224 + ph * 8) * 224
                          + pw0 * 8 + l * 4;
        float4 v[8];
        #pragma unroll
        for (int r = 0; r < 8; ++r) v[r] = *(const float4*)(base + r * 224);
        float4 acc = v[0];
        #pragma unroll
        for (int r = 1; r < 8; ++r) acc = max44(acc, v[r]);
        float m = fmax4(acc);
        m = fmaxf(m, __shfl_xor(m, 1));
        if ((l & 1) == 0) p3[g * 4 + (l >> 1)] = m;
    }
    {
        const int g = tid >> 2, l = tid & 3;
        const float* base = t2 + ((size_t)(b * 64 + g) * 112 + ph * 4) * 112
                          + pw0 * 4 + l * 4;
        float4 v[4];
        #pragma unroll
        for (int r = 0; r < 4; ++r) v[r] = *(const float4*)(base + r * 112);
        p2[g * 4 + l] = fmax4(max44(max44(v[0], v[1]), max44(v[2], v[3])));
    }
    {
        const int g = tid >> 1, l = tid & 1;
        const float* base = t1 + ((size_t)(b * 128 + g) * 56 + ph * 2) * 56
                          + pw0 * 2 + l * 4;
        float4 a = max44(*(const float4*)(base), *(const float4*)(base + 56));
        p1[g * 4 + l * 2 + 0] = fmaxf(a.x, a.y);
        p1[g * 4 + l * 2 + 1] = fmaxf(a.z, a.w);
    }
    __syncthreads();
    const int c = tid;
    const int o4 = (b * 200704 + c * 784 + ph * 28 + pw0) >> 2;
    const float4 f  = ((const float4*)ff)[o4];
    const float4 a1 = *(const float4*)&p1[(c & 127) * 4];
    const float4 a2 = *(const float4*)&p2[(c & 63) * 4];
    const float4 a3 = *(const float4*)&p3[(c & 31) * 4];
    const float4 a4 = *(const float4*)&p4[(c & 15) * 4];
    float4 o;
    o.x = fmaxf(a1.x + a2.x + a3.x + a4.x + f.x, 0.0f);
    o.y = fmaxf(a1.y + a2.y + a3.y + a4.y + f.y, 0.0f);
    o.z = fmaxf(a1.z + a2.z + a3.z + a4.z + f.z, 0.0f);
    o.w = fmaxf(a1.w + a2.w + a3.w + a4.w + f.w, 0.0f);
    ((float4*)out)[o4] = o;
}

extern "C" void kernel_launch(void* const* d_in, const int* in_sizes, int n_in,
                              void* d_out, int out_size, void* d_ws, size_t ws_size,
                              hipStream_t stream) {
    const float* t1 = (const float*)d_in[0];
    const float* t2 = (const float*)d_in[1];
    const float* t3 = (const float*)d_in[2];
    const float* t4 = (const float*)d_in[3];
    const float* ff = (const float*)d_in[4];
    float* out = (float*)d_out;

    if (ws_size >= (size_t)WS_FLOATS * sizeof(float)) {
        float* ws = (float*)d_ws;
        pool_all<<<WE1 / 4, 256, 0, stream>>>(t1, t2, t3, t4, ws);
        combine<<<1568, 256, 0, stream>>>(ws, ff, out);
    } else {
        dim3 grid(7, 28, 8);
        fused_pool_relu<<<grid, 256, 0, stream>>>(t1, t2, t3, t4, ff, out);
    }
}